// Round 19
// baseline (165.093 us; speedup 1.0000x reference)
//
#include <hip/hip_runtime.h>
#include <hip/hip_bf16.h>

#define NHEAD 8
#define CDIM 12
#define DMODEL 96
#define NBLK 128        // blocks in the counting-sort pass

__device__ __forceinline__ unsigned short f2bf(float f) {
    unsigned int u = __float_as_uint(f);
    unsigned int r = (u + 0x7fffu + ((u >> 16) & 1u)) >> 16;   // RNE
    return (unsigned short)r;
}

// ---------------- GEMM + fused att coeffs (v9: LDS-X staged, scalar W) -----
// H16[N,96](bf16) = X[N,K] @ W[K,96]. 512 thr = 8 waves per 64 nodes.
// Wave w owns cols [12w,12w+12) = head w; lane = node. X staged to LDS once
// per block, coalesced; XOR slot swizzle (kq^(node&7)). W via scalar pipe.
template<int K>
__global__ __launch_bounds__(512) void gemm_ldsx_att(
    const float* __restrict__ X, const float* __restrict__ W,
    const float* __restrict__ att_s, const float* __restrict__ att_d,
    unsigned short* __restrict__ H16, float* __restrict__ a_s,
    float* __restrict__ a_d, int N)
{
    constexpr int KQ = K / 4;
    __shared__ float xs[64 * K];       // 32 KB (K=128) / 24 KB (K=96)
    const int t = threadIdx.x;
    const int w = __builtin_amdgcn_readfirstlane(t >> 6);   // wave = head 0..7
    const int lane = t & 63;
    const int c0 = __builtin_amdgcn_readfirstlane(w * 12);
    const int n0 = blockIdx.x * 64;
    const int node = n0 + lane;
    const float4 z4 = make_float4(0.f, 0.f, 0.f, 0.f);

    // ---- stage X: coalesced global read, XOR-swizzled LDS write ----
    for (int q = t; q < 64 * KQ; q += 512) {
        const int nd = q / KQ, kq = q - nd * KQ;
        const int gn = n0 + nd;
        float4 v = z4;
        if (gn < N) v = ((const float4*)X)[(size_t)gn * KQ + kq];
        *(float4*)&xs[nd * K + 4 * (kq ^ (nd & 7))] = v;
    }

    float acc[12];
#pragma unroll
    for (int c = 0; c < 12; ++c) acc[c] = 0.f;

    __syncthreads();   // X staged; no further barriers

    const int lsw = lane & 7;
    float4 xv = *(const float4*)&xs[lane * K + 4 * (0 ^ lsw)];
    for (int k4 = 0; k4 < KQ; ++k4) {
        float4 nxt = z4;
        if (k4 + 1 < KQ)
            nxt = *(const float4*)&xs[lane * K + 4 * ((k4 + 1) ^ lsw)];
        const float xk[4] = {xv.x, xv.y, xv.z, xv.w};
#pragma unroll
        for (int kk = 0; kk < 4; ++kk) {
            const float* __restrict__ wrow = W + (size_t)(4 * k4 + kk) * 96 + c0;
#pragma unroll
            for (int c = 0; c < 12; ++c)
                acc[c] = fmaf(xk[kk], wrow[c], acc[c]);
        }
        xv = nxt;
    }

    if (node < N) {
#pragma unroll
        for (int q = 0; q < 3; ++q) {
            ushort4 hv;
            hv.x = f2bf(acc[4 * q + 0]);
            hv.y = f2bf(acc[4 * q + 1]);
            hv.z = f2bf(acc[4 * q + 2]);
            hv.w = f2bf(acc[4 * q + 3]);
            *(ushort4*)(H16 + (size_t)node * 96 + c0 + 4 * q) = hv;
        }
        float s0 = 0.f, d0 = 0.f;
#pragma unroll
        for (int i = 0; i < 12; ++i) {
            s0 = fmaf(acc[i], att_s[w * 12 + i], s0);
            d0 = fmaf(acc[i], att_d[w * 12 + i], d0);
        }
        a_s[node * NHEAD + w] = s0;
        a_d[node * NHEAD + w] = d0;
    }
}

// ---------------- CSR build: 5-dispatch counting sort ----------------------
__global__ __launch_bounds__(1024) void hist2d_kernel(
    const int* __restrict__ dsti, int* __restrict__ hist2d,
    int E0, int Etot, int nbins)
{
    __shared__ int hist[1024];
    const int t = threadIdx.x, b = blockIdx.x;
    hist[t] = 0;
    __syncthreads();
    const int chunk = (Etot + NBLK - 1) / NBLK;
    const int e0 = b * chunk;
    const int e1 = (e0 + chunk < Etot) ? e0 + chunk : Etot;
    for (int e = e0 + t; e < e1; e += 1024) {
        int d = (e < E0) ? dsti[e] : e - E0;
        atomicAdd(&hist[d >> 6], 1);
    }
    __syncthreads();
    if (t < nbins) hist2d[(size_t)t * NBLK + b] = hist[t];
}

__global__ __launch_bounds__(128) void segscan_kernel(
    const int* __restrict__ hist2d, int* __restrict__ sc2d,
    int* __restrict__ bintot)
{
    __shared__ int sh[128];
    const int b = blockIdx.x, t = threadIdx.x;
    const int v = hist2d[(size_t)b * NBLK + t];
    sh[t] = v;
    __syncthreads();
    for (int off = 1; off < 128; off <<= 1) {
        int add = (t >= off) ? sh[t - off] : 0;
        __syncthreads();
        sh[t] += add;
        __syncthreads();
    }
    sc2d[(size_t)b * NBLK + t] = sh[t] - v;   // within-bin exclusive
    if (t == 127) bintot[b] = sh[127];
}

__global__ __launch_bounds__(1024) void binscan_kernel(
    const int* __restrict__ bintot, int* __restrict__ binstart,
    int* __restrict__ rowptr, int nbins, int N, int Etot)
{
    __shared__ int sh[1024];
    const int t = threadIdx.x;
    const int v = (t < nbins) ? bintot[t] : 0;
    sh[t] = v;
    __syncthreads();
    for (int off = 1; off < 1024; off <<= 1) {
        int add = (t >= off) ? sh[t - off] : 0;
        __syncthreads();
        sh[t] += add;
        __syncthreads();
    }
    if (t < nbins) binstart[t] = sh[t] - v;
    if (t == 0) { binstart[nbins] = Etot; rowptr[N] = Etot; }
}

// records packed: (d<<16)|s  (both < 65536)
__global__ __launch_bounds__(1024) void place_kernel(
    const int* __restrict__ srci, const int* __restrict__ dsti,
    const int* __restrict__ sc2d, const int* __restrict__ binstart,
    unsigned int* __restrict__ rec, int E0, int Etot)
{
    __shared__ int run[1024];
    const int t = threadIdx.x, b = blockIdx.x;
    run[t] = 0;
    __syncthreads();
    const int chunk = (Etot + NBLK - 1) / NBLK;
    const int e0 = b * chunk;
    const int e1 = (e0 + chunk < Etot) ? e0 + chunk : Etot;
    for (int e = e0 + t; e < e1; e += 1024) {
        int s, d;
        if (e < E0) { s = srci[e]; d = dsti[e]; }
        else        { s = d = e - E0; }
        int bin = d >> 6;
        int r = atomicAdd(&run[bin], 1);
        rec[(size_t)binstart[bin] + sc2d[(size_t)bin * NBLK + b] + r] =
            ((unsigned int)d << 16) | (unsigned int)s;
    }
}

__global__ __launch_bounds__(256) void bucketCD_kernel(
    const int* __restrict__ binstart, const unsigned int* __restrict__ rec,
    int* __restrict__ rowptr, int* __restrict__ col, int N)
{
    __shared__ int deg64[64];
    __shared__ int base64[64];
    const int t = threadIdx.x, b = blockIdx.x;
    if (t < 64) deg64[t] = 0;
    __syncthreads();
    const int r0 = binstart[b], r1 = binstart[b + 1];
    for (int i = r0 + t; i < r1; i += 256)
        atomicAdd(&deg64[(rec[i] >> 16) & 63], 1);
    __syncthreads();
    if (t == 0) {
        int acc = r0;
#pragma unroll 8
        for (int i = 0; i < 64; ++i) { base64[i] = acc; acc += deg64[i]; }
    }
    __syncthreads();
    const int gn = b * 64 + t;
    if (t < 64) {
        if (gn < N) rowptr[gn] = base64[t];
        deg64[t] = 0;            // reuse as run counters
    }
    __syncthreads();
    for (int i = r0 + t; i < r1; i += 256) {
        unsigned int v = rec[i];
        int dl = (int)(v >> 16) & 63;
        int rank = atomicAdd(&deg64[dl], 1);
        col[base64[dl] + rank] = (int)(v & 0xFFFFu);
    }
}

// ---------------- edge pass v2: 16B H gathers, 12 lanes/node ---------------
// lane covers channels [8*lane, 8*lane+8) which span heads {2g2, 2g2+1},
// g2 = lane/3, r = lane%3 (r=0: all first head; r=1: 4+4; r=2: all second).
// Per edge: 1 col (broadcast), 1 float2 a_s, 1 uint4 (ushort8) H load.
__global__ __launch_bounds__(384) void edge2_vec2_kernel(
    const int* __restrict__ rowptr, const int* __restrict__ col,
    const unsigned short* __restrict__ H16, const float* __restrict__ a_s,
    const float* __restrict__ a_d, const float* __restrict__ bias,
    float* __restrict__ out, int N)
{
    const int grp  = threadIdx.x / 12;      // 32 nodes/block
    const int lane = threadIdx.x % 12;      // 8-channel chunk
    const int d = blockIdx.x * 32 + grp;
    if (d >= N) return;
    const int g2 = lane / 3;                // head pair
    const int r  = lane % 3;
    const float2 ad2 = *(const float2*)(a_d + d * NHEAD + 2 * g2);
    const uint4* __restrict__ Hc = (const uint4*)H16;   // 16B chunks, 12/row

    int j0 = rowptr[d], j1 = rowptr[d + 1];
    float4 accA = make_float4(0.f, 0.f, 0.f, 0.f);
    float4 accB = accA;
    float den0 = 1e-16f, den1 = 1e-16f;
    int j = j0;

#define EDGE_BODY(sv)                                                        \
    {                                                                        \
        const int s_ = (sv);                                                 \
        float2 a2 = *(const float2*)(a_s + s_ * NHEAD + 2 * g2);             \
        uint4  u  = Hc[(size_t)s_ * 12 + lane];                              \
        float v0 = a2.x + ad2.x, v1 = a2.y + ad2.y;                          \
        v0 = v0 > 0.f ? v0 : 0.2f * v0;                                      \
        v1 = v1 > 0.f ? v1 : 0.2f * v1;                                      \
        float e0 = __expf(v0), e1 = __expf(v1);                              \
        den0 += e0; den1 += e1;                                              \
        float mA = (r == 2) ? e1 : e0;                                       \
        float mB = (r == 0) ? e0 : e1;                                       \
        accA.x = fmaf(mA, __uint_as_float(u.x << 16),          accA.x);      \
        accA.y = fmaf(mA, __uint_as_float(u.x & 0xFFFF0000u),  accA.y);      \
        accA.z = fmaf(mA, __uint_as_float(u.y << 16),          accA.z);      \
        accA.w = fmaf(mA, __uint_as_float(u.y & 0xFFFF0000u),  accA.w);      \
        accB.x = fmaf(mB, __uint_as_float(u.z << 16),          accB.x);      \
        accB.y = fmaf(mB, __uint_as_float(u.z & 0xFFFF0000u),  accB.y);      \
        accB.z = fmaf(mB, __uint_as_float(u.w << 16),          accB.z);      \
        accB.w = fmaf(mB, __uint_as_float(u.w & 0xFFFF0000u),  accB.w);      \
    }

    for (; j + 3 < j1; j += 4) {
        const int s0 = col[j], s1 = col[j + 1], s2 = col[j + 2], s3 = col[j + 3];
        EDGE_BODY(s0); EDGE_BODY(s1); EDGE_BODY(s2); EDGE_BODY(s3);
    }
    for (; j < j1; ++j) EDGE_BODY(col[j]);
#undef EDGE_BODY

    const float inv0 = 1.0f / den0, inv1 = 1.0f / den1;
    const float invA = (r == 2) ? inv1 : inv0;
    const float invB = (r == 0) ? inv0 : inv1;
    const float4 bA = *(const float4*)(bias + lane * 8);
    const float4 bB = *(const float4*)(bias + lane * 8 + 4);
    float4 oA, oB;
    oA.x = fmaf(accA.x, invA, bA.x); oA.y = fmaf(accA.y, invA, bA.y);
    oA.z = fmaf(accA.z, invA, bA.z); oA.w = fmaf(accA.w, invA, bA.w);
    oB.x = fmaf(accB.x, invB, bB.x); oB.y = fmaf(accB.y, invB, bB.y);
    oB.z = fmaf(accB.z, invB, bB.z); oB.w = fmaf(accB.w, invB, bB.w);
    oA.x = oA.x > 0.f ? oA.x : 0.f;  oA.y = oA.y > 0.f ? oA.y : 0.f;
    oA.z = oA.z > 0.f ? oA.z : 0.f;  oA.w = oA.w > 0.f ? oA.w : 0.f;
    oB.x = oB.x > 0.f ? oB.x : 0.f;  oB.y = oB.y > 0.f ? oB.y : 0.f;
    oB.z = oB.z > 0.f ? oB.z : 0.f;  oB.w = oB.w > 0.f ? oB.w : 0.f;
    float* op = out + (size_t)d * 96 + lane * 8;
    *(float4*)op       = oA;
    *(float4*)(op + 4) = oB;
}

extern "C" void kernel_launch(void* const* d_in, const int* in_sizes, int n_in,
                              void* d_out, int out_size, void* d_ws, size_t ws_size,
                              hipStream_t stream) {
    const float* x   = (const float*)d_in[0];
    const int*   ei  = (const int*)d_in[1];
    const float* W1  = (const float*)d_in[2];
    const float* as1 = (const float*)d_in[3];
    const float* ad1 = (const float*)d_in[4];
    const float* b1  = (const float*)d_in[5];
    const float* W2  = (const float*)d_in[6];
    const float* as2 = (const float*)d_in[7];
    const float* ad2 = (const float*)d_in[8];
    const float* b2  = (const float*)d_in[9];

    const int N    = in_sizes[0] / 128;   // 50000
    const int E0   = in_sizes[1] / 2;     // 800000
    const int Etot = E0 + N;
    const int* srci = ei;
    const int* dsti = ei + E0;
    const int nbins = (N + 63) >> 6;      // 782
    const int M2    = nbins * NBLK;       // 100096

    // -------- workspace layout --------
    char* wsb = (char*)d_ws;
    unsigned short* H16 = (unsigned short*)wsb;  wsb += (size_t)N * DMODEL * 2;
    float* H1   = (float*)wsb;            wsb += (size_t)N * DMODEL * 4;
    float* AS   = (float*)wsb;            wsb += (size_t)N * NHEAD * 4;
    float* AD   = (float*)wsb;            wsb += (size_t)N * NHEAD * 4;
    int* HIST2D = (int*)wsb;              wsb += (size_t)M2 * 4;
    int* SC2D   = (int*)wsb;              wsb += (size_t)M2 * 4;
    int* BINTOT = (int*)wsb;              wsb += (size_t)nbins * 4;
    int* BINST  = (int*)wsb;              wsb += (size_t)(nbins + 1) * 4;
    int* ROWPTR = (int*)wsb;              wsb += (size_t)(N + 1) * 4;
    int* COL    = (int*)wsb;              wsb += (size_t)Etot * 4;
    unsigned int* REC = (unsigned int*)wsb; wsb += (size_t)Etot * 4;
    float* OUT  = (float*)d_out;

    const int gemm_grid = (N + 63) / 64;        // 782
    const int e2_grid   = (N + 31) / 32;        // 1563

    // -------- CSR build: 5 dispatches, no global scan chains --------
    hist2d_kernel<<<NBLK, 1024, 0, stream>>>(dsti, HIST2D, E0, Etot, nbins);
    segscan_kernel<<<nbins, 128, 0, stream>>>(HIST2D, SC2D, BINTOT);
    binscan_kernel<<<1, 1024, 0, stream>>>(BINTOT, BINST, ROWPTR, nbins, N, Etot);
    place_kernel<<<NBLK, 1024, 0, stream>>>(srci, dsti, SC2D, BINST, REC, E0, Etot);
    bucketCD_kernel<<<nbins, 256, 0, stream>>>(BINST, REC, ROWPTR, COL, N);

    // -------- layer 1 --------
    gemm_ldsx_att<128><<<gemm_grid, 512, 0, stream>>>(x, W1, as1, ad1, H16, AS, AD, N);
    edge2_vec2_kernel<<<e2_grid, 384, 0, stream>>>(ROWPTR, COL, H16, AS, AD, b1, H1, N);

    // -------- layer 2 --------
    gemm_ldsx_att<96><<<gemm_grid, 512, 0, stream>>>(H1, W2, as2, ad2, H16, AS, AD, N);
    edge2_vec2_kernel<<<e2_grid, 384, 0, stream>>>(ROWPTR, COL, H16, AS, AD, b2, OUT, N);
}

// Round 20
// 156.278 us; speedup vs baseline: 1.0564x; 1.0564x over previous
//
#include <hip/hip_runtime.h>
#include <hip/hip_bf16.h>

#define NHEAD 8
#define CDIM 12
#define DMODEL 96
#define NBLK 256        // blocks in the counting-sort pass (256 = full CU coverage)

__device__ __forceinline__ unsigned short f2bf(float f) {
    unsigned int u = __float_as_uint(f);
    unsigned int r = (u + 0x7fffu + ((u >> 16) & 1u)) >> 16;   // RNE
    return (unsigned short)r;
}

__device__ __forceinline__ float4 bf4_to_f4(ushort4 v) {
    float4 r;
    r.x = __uint_as_float((unsigned int)v.x << 16);
    r.y = __uint_as_float((unsigned int)v.y << 16);
    r.z = __uint_as_float((unsigned int)v.z << 16);
    r.w = __uint_as_float((unsigned int)v.w << 16);
    return r;
}

// ---------------- GEMM + fused att coeffs (v9: LDS-X staged, scalar W) -----
// H16[N,96](bf16) = X[N,K] @ W[K,96]. 512 thr = 8 waves per 64 nodes.
// Wave w owns cols [12w,12w+12) = head w; lane = node. X staged to LDS once
// per block, coalesced; XOR slot swizzle (kq^(node&7)). W via scalar pipe.
template<int K>
__global__ __launch_bounds__(512) void gemm_ldsx_att(
    const float* __restrict__ X, const float* __restrict__ W,
    const float* __restrict__ att_s, const float* __restrict__ att_d,
    unsigned short* __restrict__ H16, float* __restrict__ a_s,
    float* __restrict__ a_d, int N)
{
    constexpr int KQ = K / 4;
    __shared__ float xs[64 * K];       // 32 KB (K=128) / 24 KB (K=96)
    const int t = threadIdx.x;
    const int w = __builtin_amdgcn_readfirstlane(t >> 6);   // wave = head 0..7
    const int lane = t & 63;
    const int c0 = __builtin_amdgcn_readfirstlane(w * 12);
    const int n0 = blockIdx.x * 64;
    const int node = n0 + lane;
    const float4 z4 = make_float4(0.f, 0.f, 0.f, 0.f);

    // ---- stage X: coalesced global read, XOR-swizzled LDS write ----
    for (int q = t; q < 64 * KQ; q += 512) {
        const int nd = q / KQ, kq = q - nd * KQ;
        const int gn = n0 + nd;
        float4 v = z4;
        if (gn < N) v = ((const float4*)X)[(size_t)gn * KQ + kq];
        *(float4*)&xs[nd * K + 4 * (kq ^ (nd & 7))] = v;
    }

    float acc[12];
#pragma unroll
    for (int c = 0; c < 12; ++c) acc[c] = 0.f;

    __syncthreads();   // X staged; no further barriers

    const int lsw = lane & 7;
    float4 xv = *(const float4*)&xs[lane * K + 4 * (0 ^ lsw)];
    for (int k4 = 0; k4 < KQ; ++k4) {
        float4 nxt = z4;
        if (k4 + 1 < KQ)
            nxt = *(const float4*)&xs[lane * K + 4 * ((k4 + 1) ^ lsw)];
        const float xk[4] = {xv.x, xv.y, xv.z, xv.w};
#pragma unroll
        for (int kk = 0; kk < 4; ++kk) {
            const float* __restrict__ wrow = W + (size_t)(4 * k4 + kk) * 96 + c0;
#pragma unroll
            for (int c = 0; c < 12; ++c)
                acc[c] = fmaf(xk[kk], wrow[c], acc[c]);
        }
        xv = nxt;
    }

    if (node < N) {
#pragma unroll
        for (int q = 0; q < 3; ++q) {
            ushort4 hv;
            hv.x = f2bf(acc[4 * q + 0]);
            hv.y = f2bf(acc[4 * q + 1]);
            hv.z = f2bf(acc[4 * q + 2]);
            hv.w = f2bf(acc[4 * q + 3]);
            *(ushort4*)(H16 + (size_t)node * 96 + c0 + 4 * q) = hv;
        }
        float s0 = 0.f, d0 = 0.f;
#pragma unroll
        for (int i = 0; i < 12; ++i) {
            s0 = fmaf(acc[i], att_s[w * 12 + i], s0);
            d0 = fmaf(acc[i], att_d[w * 12 + i], d0);
        }
        a_s[node * NHEAD + w] = s0;
        a_d[node * NHEAD + w] = d0;
    }
}

// ---------------- CSR build: 5-dispatch counting sort ----------------------
__global__ __launch_bounds__(1024) void hist2d_kernel(
    const int* __restrict__ dsti, int* __restrict__ hist2d,
    int E0, int Etot, int nbins)
{
    __shared__ int hist[1024];
    const int t = threadIdx.x, b = blockIdx.x;
    hist[t] = 0;
    __syncthreads();
    const int chunk = (Etot + NBLK - 1) / NBLK;
    const int e0 = b * chunk;
    const int e1 = (e0 + chunk < Etot) ? e0 + chunk : Etot;
    for (int e = e0 + t; e < e1; e += 1024) {
        int d = (e < E0) ? dsti[e] : e - E0;
        atomicAdd(&hist[d >> 6], 1);
    }
    __syncthreads();
    if (t < nbins) hist2d[(size_t)t * NBLK + b] = hist[t];
}

// per-bin exclusive scan over the NBLK per-block counts (independent blocks)
__global__ __launch_bounds__(NBLK) void segscan_kernel(
    const int* __restrict__ hist2d, int* __restrict__ sc2d,
    int* __restrict__ bintot)
{
    __shared__ int sh[NBLK];
    const int b = blockIdx.x, t = threadIdx.x;
    const int v = hist2d[(size_t)b * NBLK + t];
    sh[t] = v;
    __syncthreads();
    for (int off = 1; off < NBLK; off <<= 1) {
        int add = (t >= off) ? sh[t - off] : 0;
        __syncthreads();
        sh[t] += add;
        __syncthreads();
    }
    sc2d[(size_t)b * NBLK + t] = sh[t] - v;   // within-bin exclusive
    if (t == NBLK - 1) bintot[b] = sh[NBLK - 1];
}

__global__ __launch_bounds__(1024) void binscan_kernel(
    const int* __restrict__ bintot, int* __restrict__ binstart,
    int* __restrict__ rowptr, int nbins, int N, int Etot)
{
    __shared__ int sh[1024];
    const int t = threadIdx.x;
    const int v = (t < nbins) ? bintot[t] : 0;
    sh[t] = v;
    __syncthreads();
    for (int off = 1; off < 1024; off <<= 1) {
        int add = (t >= off) ? sh[t - off] : 0;
        __syncthreads();
        sh[t] += add;
        __syncthreads();
    }
    if (t < nbins) binstart[t] = sh[t] - v;
    if (t == 0) { binstart[nbins] = Etot; rowptr[N] = Etot; }
}

// records packed: (d<<16)|s  (both < 65536)
__global__ __launch_bounds__(1024) void place_kernel(
    const int* __restrict__ srci, const int* __restrict__ dsti,
    const int* __restrict__ sc2d, const int* __restrict__ binstart,
    unsigned int* __restrict__ rec, int E0, int Etot)
{
    __shared__ int run[1024];
    const int t = threadIdx.x, b = blockIdx.x;
    run[t] = 0;
    __syncthreads();
    const int chunk = (Etot + NBLK - 1) / NBLK;
    const int e0 = b * chunk;
    const int e1 = (e0 + chunk < Etot) ? e0 + chunk : Etot;
    for (int e = e0 + t; e < e1; e += 1024) {
        int s, d;
        if (e < E0) { s = srci[e]; d = dsti[e]; }
        else        { s = d = e - E0; }
        int bin = d >> 6;
        int r = atomicAdd(&run[bin], 1);
        rec[(size_t)binstart[bin] + sc2d[(size_t)bin * NBLK + b] + r] =
            ((unsigned int)d << 16) | (unsigned int)s;
    }
}

// merged: per-bin deg histogram + rowptr write + col scatter (one kernel)
__global__ __launch_bounds__(256) void bucketCD_kernel(
    const int* __restrict__ binstart, const unsigned int* __restrict__ rec,
    int* __restrict__ rowptr, int* __restrict__ col, int N)
{
    __shared__ int deg64[64];
    __shared__ int base64[64];
    const int t = threadIdx.x, b = blockIdx.x;
    if (t < 64) deg64[t] = 0;
    __syncthreads();
    const int r0 = binstart[b], r1 = binstart[b + 1];
    for (int i = r0 + t; i < r1; i += 256)
        atomicAdd(&deg64[(rec[i] >> 16) & 63], 1);
    __syncthreads();
    if (t == 0) {
        int acc = r0;
#pragma unroll 8
        for (int i = 0; i < 64; ++i) { base64[i] = acc; acc += deg64[i]; }
    }
    __syncthreads();
    const int gn = b * 64 + t;
    if (t < 64) {
        if (gn < N) rowptr[gn] = base64[t];
        deg64[t] = 0;            // reuse as run counters
    }
    __syncthreads();
    for (int i = r0 + t; i < r1; i += 256) {
        unsigned int v = rec[i];
        int dl = (int)(v >> 16) & 63;
        int rank = atomicAdd(&deg64[dl], 1);
        col[base64[dl] + rank] = (int)(v & 0xFFFFu);
    }
}

// ---------------- edge pass (CSR): bf16 gather + fused softmax denom -------
__global__ __launch_bounds__(384) void edge2_vec_kernel(
    const int* __restrict__ rowptr, const int* __restrict__ col,
    const unsigned short* __restrict__ H16, const float* __restrict__ a_s,
    const float* __restrict__ a_d, const float* __restrict__ bias,
    float* __restrict__ out, int N)
{
    const int grp  = threadIdx.x / 24;      // 16 nodes/block
    const int lane = threadIdx.x % 24;      // 4-channel chunk
    const int d = blockIdx.x * 16 + grp;
    if (d >= N) return;
    const int hh = lane / 3;
    const float ad  = a_d[d * NHEAD + hh];
    const ushort4* __restrict__ Hc = (const ushort4*)H16;

    int j0 = rowptr[d], j1 = rowptr[d + 1];
    float4 acc = make_float4(0.f, 0.f, 0.f, 0.f);
    float den = 1e-16f;
    int j = j0;
    for (; j + 3 < j1; j += 4) {
        int s0 = col[j], s1 = col[j+1], s2 = col[j+2], s3 = col[j+3];
        float v0 = a_s[s0 * NHEAD + hh] + ad;
        float v1 = a_s[s1 * NHEAD + hh] + ad;
        float v2 = a_s[s2 * NHEAD + hh] + ad;
        float v3 = a_s[s3 * NHEAD + hh] + ad;
        ushort4 u0 = Hc[(size_t)s0 * 24 + lane];
        ushort4 u1 = Hc[(size_t)s1 * 24 + lane];
        ushort4 u2 = Hc[(size_t)s2 * 24 + lane];
        ushort4 u3 = Hc[(size_t)s3 * 24 + lane];
        v0 = v0 > 0.f ? v0 : 0.2f * v0;
        v1 = v1 > 0.f ? v1 : 0.2f * v1;
        v2 = v2 > 0.f ? v2 : 0.2f * v2;
        v3 = v3 > 0.f ? v3 : 0.2f * v3;
        float e0 = __expf(v0), e1 = __expf(v1), e2 = __expf(v2), e3 = __expf(v3);
        den += e0 + e1 + e2 + e3;
        float4 h0 = bf4_to_f4(u0), h1 = bf4_to_f4(u1);
        float4 h2 = bf4_to_f4(u2), h3 = bf4_to_f4(u3);
        acc.x = fmaf(e0, h0.x, acc.x); acc.y = fmaf(e0, h0.y, acc.y);
        acc.z = fmaf(e0, h0.z, acc.z); acc.w = fmaf(e0, h0.w, acc.w);
        acc.x = fmaf(e1, h1.x, acc.x); acc.y = fmaf(e1, h1.y, acc.y);
        acc.z = fmaf(e1, h1.z, acc.z); acc.w = fmaf(e1, h1.w, acc.w);
        acc.x = fmaf(e2, h2.x, acc.x); acc.y = fmaf(e2, h2.y, acc.y);
        acc.z = fmaf(e2, h2.z, acc.z); acc.w = fmaf(e2, h2.w, acc.w);
        acc.x = fmaf(e3, h3.x, acc.x); acc.y = fmaf(e3, h3.y, acc.y);
        acc.z = fmaf(e3, h3.z, acc.z); acc.w = fmaf(e3, h3.w, acc.w);
    }
    for (; j < j1; ++j) {
        int s = col[j];
        float v = a_s[s * NHEAD + hh] + ad;
        v = v > 0.f ? v : 0.2f * v;
        float ex = __expf(v);
        den += ex;
        float4 hv = bf4_to_f4(Hc[(size_t)s * 24 + lane]);
        acc.x = fmaf(ex, hv.x, acc.x); acc.y = fmaf(ex, hv.y, acc.y);
        acc.z = fmaf(ex, hv.z, acc.z); acc.w = fmaf(ex, hv.w, acc.w);
    }
    float inv = 1.0f / den;
    float4 bv = ((const float4*)bias)[lane];
    float4 o;
    o.x = fmaf(acc.x, inv, bv.x); o.y = fmaf(acc.y, inv, bv.y);
    o.z = fmaf(acc.z, inv, bv.z); o.w = fmaf(acc.w, inv, bv.w);
    o.x = o.x > 0.f ? o.x : 0.f;  o.y = o.y > 0.f ? o.y : 0.f;
    o.z = o.z > 0.f ? o.z : 0.f;  o.w = o.w > 0.f ? o.w : 0.f;
    ((float4*)out)[(size_t)d * 24 + lane] = o;
}

extern "C" void kernel_launch(void* const* d_in, const int* in_sizes, int n_in,
                              void* d_out, int out_size, void* d_ws, size_t ws_size,
                              hipStream_t stream) {
    const float* x   = (const float*)d_in[0];
    const int*   ei  = (const int*)d_in[1];
    const float* W1  = (const float*)d_in[2];
    const float* as1 = (const float*)d_in[3];
    const float* ad1 = (const float*)d_in[4];
    const float* b1  = (const float*)d_in[5];
    const float* W2  = (const float*)d_in[6];
    const float* as2 = (const float*)d_in[7];
    const float* ad2 = (const float*)d_in[8];
    const float* b2  = (const float*)d_in[9];

    const int N    = in_sizes[0] / 128;   // 50000
    const int E0   = in_sizes[1] / 2;     // 800000
    const int Etot = E0 + N;
    const int* srci = ei;
    const int* dsti = ei + E0;
    const int nbins = (N + 63) >> 6;      // 782
    const int M2    = nbins * NBLK;       // 200192

    // -------- workspace layout --------
    char* wsb = (char*)d_ws;
    unsigned short* H16 = (unsigned short*)wsb;  wsb += (size_t)N * DMODEL * 2;
    float* H1   = (float*)wsb;            wsb += (size_t)N * DMODEL * 4;
    float* AS   = (float*)wsb;            wsb += (size_t)N * NHEAD * 4;
    float* AD   = (float*)wsb;            wsb += (size_t)N * NHEAD * 4;
    int* HIST2D = (int*)wsb;              wsb += (size_t)M2 * 4;
    int* SC2D   = (int*)wsb;              wsb += (size_t)M2 * 4;
    int* BINTOT = (int*)wsb;              wsb += (size_t)nbins * 4;
    int* BINST  = (int*)wsb;              wsb += (size_t)(nbins + 1) * 4;
    int* ROWPTR = (int*)wsb;              wsb += (size_t)(N + 1) * 4;
    int* COL    = (int*)wsb;              wsb += (size_t)Etot * 4;
    unsigned int* REC = (unsigned int*)wsb; wsb += (size_t)Etot * 4;
    float* OUT  = (float*)d_out;

    const int gemm_grid = (N + 63) / 64;        // 782
    const int e2_grid   = (N + 15) / 16;

    // -------- CSR build: 5 dispatches, no global scan chains --------
    hist2d_kernel<<<NBLK, 1024, 0, stream>>>(dsti, HIST2D, E0, Etot, nbins);
    segscan_kernel<<<nbins, NBLK, 0, stream>>>(HIST2D, SC2D, BINTOT);
    binscan_kernel<<<1, 1024, 0, stream>>>(BINTOT, BINST, ROWPTR, nbins, N, Etot);
    place_kernel<<<NBLK, 1024, 0, stream>>>(srci, dsti, SC2D, BINST, REC, E0, Etot);
    bucketCD_kernel<<<nbins, 256, 0, stream>>>(BINST, REC, ROWPTR, COL, N);

    // -------- layer 1 --------
    gemm_ldsx_att<128><<<gemm_grid, 512, 0, stream>>>(x, W1, as1, ad1, H16, AS, AD, N);
    edge2_vec_kernel<<<e2_grid, 384, 0, stream>>>(ROWPTR, COL, H16, AS, AD, b1, H1, N);

    // -------- layer 2 --------
    gemm_ldsx_att<96><<<gemm_grid, 512, 0, stream>>>(H1, W2, as2, ad2, H16, AS, AD, N);
    edge2_vec_kernel<<<e2_grid, 384, 0, stream>>>(ROWPTR, COL, H16, AS, AD, b2, OUT, N);
}

// Round 21
// 155.447 us; speedup vs baseline: 1.0621x; 1.0053x over previous
//
#include <hip/hip_runtime.h>
#include <hip/hip_bf16.h>

#define NHEAD 8
#define CDIM 12
#define DMODEL 96
#define NBLK 256        // blocks in the counting-sort pass (256 = full CU coverage)

__device__ __forceinline__ unsigned short f2bf(float f) {
    unsigned int u = __float_as_uint(f);
    unsigned int r = (u + 0x7fffu + ((u >> 16) & 1u)) >> 16;   // RNE
    return (unsigned short)r;
}

__device__ __forceinline__ float4 bf4_to_f4(ushort4 v) {
    float4 r;
    r.x = __uint_as_float((unsigned int)v.x << 16);
    r.y = __uint_as_float((unsigned int)v.y << 16);
    r.z = __uint_as_float((unsigned int)v.z << 16);
    r.w = __uint_as_float((unsigned int)v.w << 16);
    return r;
}

// ---------------- GEMM + fused att coeffs (v10: LDS-X staged, scalar W) ----
// H16[N,96](bf16) = X[N,K] @ W[K,96]. 512 thr = 8 waves per 64 nodes.
// Wave w owns cols [12w,12w+12) = head w; lane = node. X staged to LDS once
// per block (fp32 path: float4 chunks; bf16 path: uint4 = 8ch chunks ->
// two float4 slots (2q)^key,(2q+1)^key). W via scalar pipe.
template<int K, bool BF16IN>
__global__ __launch_bounds__(512) void gemm_ldsx_att(
    const void* __restrict__ Xv, const float* __restrict__ W,
    const float* __restrict__ att_s, const float* __restrict__ att_d,
    unsigned short* __restrict__ H16, float* __restrict__ a_s,
    float* __restrict__ a_d, int N)
{
    constexpr int KQ = K / 4;
    __shared__ float xs[64 * K];       // 32 KB (K=128) / 24 KB (K=96)
    const int t = threadIdx.x;
    const int w = __builtin_amdgcn_readfirstlane(t >> 6);   // wave = head 0..7
    const int lane = t & 63;
    const int c0 = __builtin_amdgcn_readfirstlane(w * 12);
    const int n0 = blockIdx.x * 64;
    const int node = n0 + lane;
    const float4 z4 = make_float4(0.f, 0.f, 0.f, 0.f);

    // ---- stage X: coalesced global read, XOR-swizzled LDS write ----
    if constexpr (BF16IN) {
        const uint4* __restrict__ Xb = (const uint4*)Xv;   // 8 bf16 per chunk
        constexpr int C8 = K / 8;                          // 12 for K=96
        for (int q = t; q < 64 * C8; q += 512) {
            const int nd = q / C8, ck = q - nd * C8;
            const int gn = n0 + nd;
            uint4 u = make_uint4(0u, 0u, 0u, 0u);
            if (gn < N) u = Xb[(size_t)gn * C8 + ck];
            float4 A, B;
            A.x = __uint_as_float(u.x << 16);
            A.y = __uint_as_float(u.x & 0xFFFF0000u);
            A.z = __uint_as_float(u.y << 16);
            A.w = __uint_as_float(u.y & 0xFFFF0000u);
            B.x = __uint_as_float(u.z << 16);
            B.y = __uint_as_float(u.z & 0xFFFF0000u);
            B.z = __uint_as_float(u.w << 16);
            B.w = __uint_as_float(u.w & 0xFFFF0000u);
            const int key = nd & 7;
            *(float4*)&xs[nd * K + 4 * ((2 * ck)     ^ key)] = A;
            *(float4*)&xs[nd * K + 4 * ((2 * ck + 1) ^ key)] = B;
        }
    } else {
        const float* __restrict__ X = (const float*)Xv;
        for (int q = t; q < 64 * KQ; q += 512) {
            const int nd = q / KQ, kq = q - nd * KQ;
            const int gn = n0 + nd;
            float4 v = z4;
            if (gn < N) v = ((const float4*)X)[(size_t)gn * KQ + kq];
            *(float4*)&xs[nd * K + 4 * (kq ^ (nd & 7))] = v;
        }
    }

    float acc[12];
#pragma unroll
    for (int c = 0; c < 12; ++c) acc[c] = 0.f;

    __syncthreads();   // X staged; no further barriers

    const int lsw = lane & 7;
    float4 xv = *(const float4*)&xs[lane * K + 4 * (0 ^ lsw)];
    for (int k4 = 0; k4 < KQ; ++k4) {
        float4 nxt = z4;
        if (k4 + 1 < KQ)
            nxt = *(const float4*)&xs[lane * K + 4 * ((k4 + 1) ^ lsw)];
        const float xk[4] = {xv.x, xv.y, xv.z, xv.w};
#pragma unroll
        for (int kk = 0; kk < 4; ++kk) {
            const float* __restrict__ wrow = W + (size_t)(4 * k4 + kk) * 96 + c0;
#pragma unroll
            for (int c = 0; c < 12; ++c)
                acc[c] = fmaf(xk[kk], wrow[c], acc[c]);
        }
        xv = nxt;
    }

    if (node < N) {
#pragma unroll
        for (int q = 0; q < 3; ++q) {
            ushort4 hv;
            hv.x = f2bf(acc[4 * q + 0]);
            hv.y = f2bf(acc[4 * q + 1]);
            hv.z = f2bf(acc[4 * q + 2]);
            hv.w = f2bf(acc[4 * q + 3]);
            *(ushort4*)(H16 + (size_t)node * 96 + c0 + 4 * q) = hv;
        }
        float s0 = 0.f, d0 = 0.f;
#pragma unroll
        for (int i = 0; i < 12; ++i) {
            s0 = fmaf(acc[i], att_s[w * 12 + i], s0);
            d0 = fmaf(acc[i], att_d[w * 12 + i], d0);
        }
        a_s[node * NHEAD + w] = s0;
        a_d[node * NHEAD + w] = d0;
    }
}

// ---------------- CSR build: 5-dispatch counting sort ----------------------
__global__ __launch_bounds__(1024) void hist2d_kernel(
    const int* __restrict__ dsti, int* __restrict__ hist2d,
    int E0, int Etot, int nbins)
{
    __shared__ int hist[1024];
    const int t = threadIdx.x, b = blockIdx.x;
    hist[t] = 0;
    __syncthreads();
    const int chunk = (Etot + NBLK - 1) / NBLK;
    const int e0 = b * chunk;
    const int e1 = (e0 + chunk < Etot) ? e0 + chunk : Etot;
    for (int e = e0 + t; e < e1; e += 1024) {
        int d = (e < E0) ? dsti[e] : e - E0;
        atomicAdd(&hist[d >> 6], 1);
    }
    __syncthreads();
    if (t < nbins) hist2d[(size_t)t * NBLK + b] = hist[t];
}

// per-bin exclusive scan over the NBLK per-block counts (independent blocks)
__global__ __launch_bounds__(NBLK) void segscan_kernel(
    const int* __restrict__ hist2d, int* __restrict__ sc2d,
    int* __restrict__ bintot)
{
    __shared__ int sh[NBLK];
    const int b = blockIdx.x, t = threadIdx.x;
    const int v = hist2d[(size_t)b * NBLK + t];
    sh[t] = v;
    __syncthreads();
    for (int off = 1; off < NBLK; off <<= 1) {
        int add = (t >= off) ? sh[t - off] : 0;
        __syncthreads();
        sh[t] += add;
        __syncthreads();
    }
    sc2d[(size_t)b * NBLK + t] = sh[t] - v;   // within-bin exclusive
    if (t == NBLK - 1) bintot[b] = sh[NBLK - 1];
}

__global__ __launch_bounds__(1024) void binscan_kernel(
    const int* __restrict__ bintot, int* __restrict__ binstart,
    int* __restrict__ rowptr, int nbins, int N, int Etot)
{
    __shared__ int sh[1024];
    const int t = threadIdx.x;
    const int v = (t < nbins) ? bintot[t] : 0;
    sh[t] = v;
    __syncthreads();
    for (int off = 1; off < 1024; off <<= 1) {
        int add = (t >= off) ? sh[t - off] : 0;
        __syncthreads();
        sh[t] += add;
        __syncthreads();
    }
    if (t < nbins) binstart[t] = sh[t] - v;
    if (t == 0) { binstart[nbins] = Etot; rowptr[N] = Etot; }
}

// records packed: (d<<16)|s  (both < 65536)
__global__ __launch_bounds__(1024) void place_kernel(
    const int* __restrict__ srci, const int* __restrict__ dsti,
    const int* __restrict__ sc2d, const int* __restrict__ binstart,
    unsigned int* __restrict__ rec, int E0, int Etot)
{
    __shared__ int run[1024];
    const int t = threadIdx.x, b = blockIdx.x;
    run[t] = 0;
    __syncthreads();
    const int chunk = (Etot + NBLK - 1) / NBLK;
    const int e0 = b * chunk;
    const int e1 = (e0 + chunk < Etot) ? e0 + chunk : Etot;
    for (int e = e0 + t; e < e1; e += 1024) {
        int s, d;
        if (e < E0) { s = srci[e]; d = dsti[e]; }
        else        { s = d = e - E0; }
        int bin = d >> 6;
        int r = atomicAdd(&run[bin], 1);
        rec[(size_t)binstart[bin] + sc2d[(size_t)bin * NBLK + b] + r] =
            ((unsigned int)d << 16) | (unsigned int)s;
    }
}

// merged: per-bin deg histogram + rowptr write + col scatter (one kernel)
__global__ __launch_bounds__(256) void bucketCD_kernel(
    const int* __restrict__ binstart, const unsigned int* __restrict__ rec,
    int* __restrict__ rowptr, int* __restrict__ col, int N)
{
    __shared__ int deg64[64];
    __shared__ int base64[64];
    const int t = threadIdx.x, b = blockIdx.x;
    if (t < 64) deg64[t] = 0;
    __syncthreads();
    const int r0 = binstart[b], r1 = binstart[b + 1];
    for (int i = r0 + t; i < r1; i += 256)
        atomicAdd(&deg64[(rec[i] >> 16) & 63], 1);
    __syncthreads();
    if (t == 0) {
        int acc = r0;
#pragma unroll 8
        for (int i = 0; i < 64; ++i) { base64[i] = acc; acc += deg64[i]; }
    }
    __syncthreads();
    const int gn = b * 64 + t;
    if (t < 64) {
        if (gn < N) rowptr[gn] = base64[t];
        deg64[t] = 0;            // reuse as run counters
    }
    __syncthreads();
    for (int i = r0 + t; i < r1; i += 256) {
        unsigned int v = rec[i];
        int dl = (int)(v >> 16) & 63;
        int rank = atomicAdd(&deg64[dl], 1);
        col[base64[dl] + rank] = (int)(v & 0xFFFFu);
    }
}

// ---------------- edge pass (CSR): bf16 gather + fused softmax denom -------
// BF16OUT: layer-1 writes bf16 H1 (halves the H1 round-trip); layer-2 fp32.
template<bool BF16OUT>
__global__ __launch_bounds__(384) void edge2_vec_kernel(
    const int* __restrict__ rowptr, const int* __restrict__ col,
    const unsigned short* __restrict__ H16, const float* __restrict__ a_s,
    const float* __restrict__ a_d, const float* __restrict__ bias,
    void* __restrict__ outv, int N)
{
    const int grp  = threadIdx.x / 24;      // 16 nodes/block
    const int lane = threadIdx.x % 24;      // 4-channel chunk
    const int d = blockIdx.x * 16 + grp;
    if (d >= N) return;
    const int hh = lane / 3;
    const float ad  = a_d[d * NHEAD + hh];
    const ushort4* __restrict__ Hc = (const ushort4*)H16;

    int j0 = rowptr[d], j1 = rowptr[d + 1];
    float4 acc = make_float4(0.f, 0.f, 0.f, 0.f);
    float den = 1e-16f;
    int j = j0;
    for (; j + 3 < j1; j += 4) {
        int s0 = col[j], s1 = col[j+1], s2 = col[j+2], s3 = col[j+3];
        float v0 = a_s[s0 * NHEAD + hh] + ad;
        float v1 = a_s[s1 * NHEAD + hh] + ad;
        float v2 = a_s[s2 * NHEAD + hh] + ad;
        float v3 = a_s[s3 * NHEAD + hh] + ad;
        ushort4 u0 = Hc[(size_t)s0 * 24 + lane];
        ushort4 u1 = Hc[(size_t)s1 * 24 + lane];
        ushort4 u2 = Hc[(size_t)s2 * 24 + lane];
        ushort4 u3 = Hc[(size_t)s3 * 24 + lane];
        v0 = v0 > 0.f ? v0 : 0.2f * v0;
        v1 = v1 > 0.f ? v1 : 0.2f * v1;
        v2 = v2 > 0.f ? v2 : 0.2f * v2;
        v3 = v3 > 0.f ? v3 : 0.2f * v3;
        float e0 = __expf(v0), e1 = __expf(v1), e2 = __expf(v2), e3 = __expf(v3);
        den += e0 + e1 + e2 + e3;
        float4 h0 = bf4_to_f4(u0), h1 = bf4_to_f4(u1);
        float4 h2 = bf4_to_f4(u2), h3 = bf4_to_f4(u3);
        acc.x = fmaf(e0, h0.x, acc.x); acc.y = fmaf(e0, h0.y, acc.y);
        acc.z = fmaf(e0, h0.z, acc.z); acc.w = fmaf(e0, h0.w, acc.w);
        acc.x = fmaf(e1, h1.x, acc.x); acc.y = fmaf(e1, h1.y, acc.y);
        acc.z = fmaf(e1, h1.z, acc.z); acc.w = fmaf(e1, h1.w, acc.w);
        acc.x = fmaf(e2, h2.x, acc.x); acc.y = fmaf(e2, h2.y, acc.y);
        acc.z = fmaf(e2, h2.z, acc.z); acc.w = fmaf(e2, h2.w, acc.w);
        acc.x = fmaf(e3, h3.x, acc.x); acc.y = fmaf(e3, h3.y, acc.y);
        acc.z = fmaf(e3, h3.z, acc.z); acc.w = fmaf(e3, h3.w, acc.w);
    }
    for (; j < j1; ++j) {
        int s = col[j];
        float v = a_s[s * NHEAD + hh] + ad;
        v = v > 0.f ? v : 0.2f * v;
        float ex = __expf(v);
        den += ex;
        float4 hv = bf4_to_f4(Hc[(size_t)s * 24 + lane]);
        acc.x = fmaf(ex, hv.x, acc.x); acc.y = fmaf(ex, hv.y, acc.y);
        acc.z = fmaf(ex, hv.z, acc.z); acc.w = fmaf(ex, hv.w, acc.w);
    }
    float inv = 1.0f / den;
    float4 bv = ((const float4*)bias)[lane];
    float4 o;
    o.x = fmaf(acc.x, inv, bv.x); o.y = fmaf(acc.y, inv, bv.y);
    o.z = fmaf(acc.z, inv, bv.z); o.w = fmaf(acc.w, inv, bv.w);
    o.x = o.x > 0.f ? o.x : 0.f;  o.y = o.y > 0.f ? o.y : 0.f;
    o.z = o.z > 0.f ? o.z : 0.f;  o.w = o.w > 0.f ? o.w : 0.f;
    if constexpr (BF16OUT) {
        ushort4 ov;
        ov.x = f2bf(o.x); ov.y = f2bf(o.y); ov.z = f2bf(o.z); ov.w = f2bf(o.w);
        ((ushort4*)outv)[(size_t)d * 24 + lane] = ov;
    } else {
        ((float4*)outv)[(size_t)d * 24 + lane] = o;
    }
}

extern "C" void kernel_launch(void* const* d_in, const int* in_sizes, int n_in,
                              void* d_out, int out_size, void* d_ws, size_t ws_size,
                              hipStream_t stream) {
    const float* x   = (const float*)d_in[0];
    const int*   ei  = (const int*)d_in[1];
    const float* W1  = (const float*)d_in[2];
    const float* as1 = (const float*)d_in[3];
    const float* ad1 = (const float*)d_in[4];
    const float* b1  = (const float*)d_in[5];
    const float* W2  = (const float*)d_in[6];
    const float* as2 = (const float*)d_in[7];
    const float* ad2 = (const float*)d_in[8];
    const float* b2  = (const float*)d_in[9];

    const int N    = in_sizes[0] / 128;   // 50000
    const int E0   = in_sizes[1] / 2;     // 800000
    const int Etot = E0 + N;
    const int* srci = ei;
    const int* dsti = ei + E0;
    const int nbins = (N + 63) >> 6;      // 782
    const int M2    = nbins * NBLK;       // 200192

    // -------- workspace layout --------
    char* wsb = (char*)d_ws;
    unsigned short* H16 = (unsigned short*)wsb;  wsb += (size_t)N * DMODEL * 2;
    unsigned short* H1b = (unsigned short*)wsb;  wsb += (size_t)N * DMODEL * 2;
    float* AS   = (float*)wsb;            wsb += (size_t)N * NHEAD * 4;
    float* AD   = (float*)wsb;            wsb += (size_t)N * NHEAD * 4;
    int* HIST2D = (int*)wsb;              wsb += (size_t)M2 * 4;
    int* SC2D   = (int*)wsb;              wsb += (size_t)M2 * 4;
    int* BINTOT = (int*)wsb;              wsb += (size_t)nbins * 4;
    int* BINST  = (int*)wsb;              wsb += (size_t)(nbins + 1) * 4;
    int* ROWPTR = (int*)wsb;              wsb += (size_t)(N + 1) * 4;
    int* COL    = (int*)wsb;              wsb += (size_t)Etot * 4;
    unsigned int* REC = (unsigned int*)wsb; wsb += (size_t)Etot * 4;
    float* OUT  = (float*)d_out;

    const int gemm_grid = (N + 63) / 64;        // 782
    const int e2_grid   = (N + 15) / 16;

    // -------- CSR build: 5 dispatches, no global scan chains --------
    hist2d_kernel<<<NBLK, 1024, 0, stream>>>(dsti, HIST2D, E0, Etot, nbins);
    segscan_kernel<<<nbins, NBLK, 0, stream>>>(HIST2D, SC2D, BINTOT);
    binscan_kernel<<<1, 1024, 0, stream>>>(BINTOT, BINST, ROWPTR, nbins, N, Etot);
    place_kernel<<<NBLK, 1024, 0, stream>>>(srci, dsti, SC2D, BINST, REC, E0, Etot);
    bucketCD_kernel<<<nbins, 256, 0, stream>>>(BINST, REC, ROWPTR, COL, N);

    // -------- layer 1 --------
    gemm_ldsx_att<128, false><<<gemm_grid, 512, 0, stream>>>(
        x, W1, as1, ad1, H16, AS, AD, N);
    edge2_vec_kernel<true><<<e2_grid, 384, 0, stream>>>(
        ROWPTR, COL, H16, AS, AD, b1, H1b, N);

    // -------- layer 2 --------
    gemm_ldsx_att<96, true><<<gemm_grid, 512, 0, stream>>>(
        H1b, W2, as2, ad2, H16, AS, AD, N);
    edge2_vec_kernel<false><<<e2_grid, 384, 0, stream>>>(
        ROWPTR, COL, H16, AS, AD, b2, OUT, N);
}